// Round 3
// baseline (143.675 us; speedup 1.0000x reference)
//
#include <hip/hip_runtime.h>
#include <hip/hip_bf16.h>

// ConvDeepSet, two-kernel scheme:
//  prep:  co fp32 -> bf16 in B-frag chunk layout [b][n>>3][c][n&7] (ws, 4MB)
//         sx[b][n] = s * x[n][b] fp32 (ws, 128KB),  s = sqrt(0.5*log2e)/ls
//         Wt[:,1:] -> bf16 frag layout [ch][r][8c] (ws, 16KB)
//  main:  per wave (32 m): K[m][n]=exp2(-(sx-sy)^2) generated in-register in
//         A-frag layout; V = K @ co via 32x32x16 bf16 MFMA, B-frags streamed
//         from ws (L2) with 1-deep prefetch; dens stays exact fp32 VALU.
//         Barrier-free k-loop (1 __syncthreads total for x staging).

#define N_CTX 2048
#define BATCH 16
#define M_TGT 4096
#define COUT  64
#define RDIM  128

#define WS_CO_BYTES (N_CTX * BATCH * COUT * 2)        // 4 MB
#define WS_SX_OFF   WS_CO_BYTES                        // 128 KB fp32
#define WS_WT_OFF   (WS_SX_OFF + N_CTX * BATCH * 4)    // 16 KB bf16

#define SSCALE 0.8493222f   // sqrt(0.5 * log2(e))

typedef __attribute__((ext_vector_type(8)))  short        bf16x8;
typedef __attribute__((ext_vector_type(4)))  unsigned int uint4v;
typedef __attribute__((ext_vector_type(16))) float        floatx16;

#if __has_builtin(__builtin_amdgcn_exp2f)
#define EXP2F __builtin_amdgcn_exp2f
#else
#define EXP2F exp2f
#endif

static __device__ __forceinline__ unsigned int pack_bf16(float lo, float hi) {
    __hip_bfloat162 h = __float22bfloat162_rn(make_float2(lo, hi));
    return *reinterpret_cast<unsigned int*>(&h);
}
static __device__ __forceinline__ unsigned short f2bf(float f) {
    __hip_bfloat16 h = __float2bfloat16(f);
    return *reinterpret_cast<unsigned short*>(&h);
}

__global__ __launch_bounds__(256)
void convdeepset_prep(const float* __restrict__ ci, const float* __restrict__ co,
                      const float* __restrict__ ls, const float* __restrict__ W,
                      unsigned char* __restrict__ ws)
{
    unsigned short* cow = (unsigned short*)ws;
    float*          sx  = (float*)(ws + WS_SX_OFF);
    unsigned short* wt  = (unsigned short*)(ws + WS_WT_OFF);
    const int blk = blockIdx.x, tid = threadIdx.x;

    if (blk < 4096) {
        // co: 1M n-pairs; reads coalesced along c, writes bf16-pair along n
        const int f  = blk * 256 + tid;
        const int c  = f & 63;
        const int bb = (f >> 6) & 15;
        const int n  = (f >> 10) * 2;          // even n
        const float f0 = co[((size_t)n       * BATCH + bb) * COUT + c];
        const float f1 = co[((size_t)(n + 1) * BATCH + bb) * COUT + c];
        const int gch = n >> 3, e = n & 7;
        *(unsigned int*)&cow[bb * 131072 + gch * 512 + c * 8 + e] = pack_bf16(f0, f1);
    } else if (blk < 4224) {
        const int f = (blk - 4096) * 256 + tid;   // 0..32767
        const int n = f & 2047, bb = f >> 11;
        const float s = SSCALE / ls[0];
        sx[bb * 2048 + n] = s * ci[(size_t)n * BATCH + bb];
    } else {
        for (int f = tid; f < 8192; f += 256) {
            const int cp = f & 7, r = (f >> 3) & 127, ch = f >> 10;
            wt[ch * 1024 + r * 8 + cp] = f2bf(W[r * 65 + 1 + ch * 8 + cp]);
        }
    }
}

__global__ __launch_bounds__(128)
void convdeepset_main(const float* __restrict__ ti, const float* __restrict__ ls,
                      const float* __restrict__ W,  const float* __restrict__ bias,
                      const unsigned char* __restrict__ ws, float* __restrict__ out)
{
    __shared__ float sxt[N_CTX];                    // 8 KB  scaled x, whole batch
    __shared__ unsigned short vstage[2][2048];      // 8 KB  per-wave V, A-frag layout

    const int tid  = threadIdx.x;
    const int lane = tid & 63;
    const int wv   = tid >> 6;        // 0..1
    const int g    = lane >> 5;       // MFMA k-group
    const int l31  = lane & 31;
    const int b    = blockIdx.x >> 6; // 0..15
    const int mt   = blockIdx.x & 63; // 0..63
    const int m0   = mt * 64 + wv * 32;

    // stage scaled x (coalesced float4; 16 floats/thread)
    const float4* sxg = (const float4*)(ws + WS_SX_OFF) + b * (N_CTX / 4);
    float4* sxt4 = (float4*)sxt;
#pragma unroll
    for (int q = 0; q < 4; ++q) sxt4[q * 128 + tid] = sxg[q * 128 + tid];

    const float s  = SSCALE / ls[0];
    const float sy = s * ti[(size_t)(m0 + l31) * BATCH + b];
    __syncthreads();

    // B-frag stream base: bf16 index b*131072 + (ks*2+g)*512 + l31*8
    const unsigned short* cow = (const unsigned short*)ws
                              + (size_t)b * 131072 + g * 512 + l31 * 8;

    floatx16 acc0, acc1;
#pragma unroll
    for (int i = 0; i < 16; ++i) { acc0[i] = 0.0f; acc1[i] = 0.0f; }
    float dens = 0.0f;

    bf16x8 cb0 = *(const bf16x8*)(cow);
    bf16x8 cb1 = *(const bf16x8*)(cow + 256);
    float4 xa  = *(const float4*)&sxt[g * 8];
    float4 xb  = *(const float4*)&sxt[g * 8 + 4];

    for (int ks = 0; ks < 128; ++ks) {
        bf16x8 nb0 = cb0, nb1 = cb1; float4 nxa = xa, nxb = xb;
        if (ks < 127) {                       // 1-deep prefetch (no barriers in loop)
            const unsigned short* p = cow + (ks + 1) * 1024;
            nb0 = *(const bf16x8*)(p);
            nb1 = *(const bf16x8*)(p + 256);
            nxa = *(const float4*)&sxt[(ks + 1) * 16 + g * 8];
            nxb = *(const float4*)&sxt[(ks + 1) * 16 + g * 8 + 4];
        }
        const float xs[8] = {xa.x, xa.y, xa.z, xa.w, xb.x, xb.y, xb.z, xb.w};
        float kv[8];
#pragma unroll
        for (int j = 0; j < 8; ++j) {
            const float t = xs[j] - sy;
            kv[j] = EXP2F(-(t * t));          // neg folds into v_exp_f32 modifier
            dens += kv[j];                    // density stays exact fp32
        }
        uint4v aw;
#pragma unroll
        for (int q = 0; q < 4; ++q) aw[q] = pack_bf16(kv[2 * q], kv[2 * q + 1]);
        const bf16x8 av = __builtin_bit_cast(bf16x8, aw);
        acc0 = __builtin_amdgcn_mfma_f32_32x32x16_bf16(av, cb0, acc0, 0, 0, 0);
        acc1 = __builtin_amdgcn_mfma_f32_32x32x16_bf16(av, cb1, acc1, 0, 0, 0);
        cb0 = nb0; cb1 = nb1; xa = nxa; xb = nxb;
    }

    // complete density: same m lives at lane^32
    dens += __shfl_xor(dens, 32);

    // normalize channels, stage V (bf16, A-frag layout) to this wave's LDS region
    float drow[16];
    unsigned short* vs = vstage[wv];
#pragma unroll
    for (int reg = 0; reg < 16; ++reg) {
        const int row = (reg & 3) + 8 * (reg >> 2) + 4 * g;   // verified 32x32 C/D map
        const float dr = __shfl(dens, row);
        drow[reg] = dr;
        const float dinv = 1.0f / (dr + 1e-8f);
        const int c0 = l31, c1 = 32 + l31;
        vs[(c0 >> 3) * 256 + row * 8 + (c0 & 7)] = f2bf(acc0[reg] * dinv);
        vs[(c1 >> 3) * 256 + row * 8 + (c1 & 7)] = f2bf(acc1[reg] * dinv);
    }

    // projection GEMM: D[32m][128r] = V[32m][64c] * Wt[64c][128r]; Wt streamed from L2
    const unsigned short* wtg = (const unsigned short*)(ws + WS_WT_OFF);
    floatx16 pacc[4];
#pragma unroll
    for (int rt = 0; rt < 4; ++rt)
#pragma unroll
        for (int i = 0; i < 16; ++i) pacc[rt][i] = 0.0f;

#pragma unroll
    for (int s2 = 0; s2 < 4; ++s2) {
        const int ch = 2 * s2 + g;
        const bf16x8 avp = *(const bf16x8*)&vs[ch * 256 + l31 * 8];
#pragma unroll
        for (int rt = 0; rt < 4; ++rt) {
            const bf16x8 bvp = *(const bf16x8*)&wtg[ch * 1024 + (rt * 32 + l31) * 8];
            pacc[rt] = __builtin_amdgcn_mfma_f32_32x32x16_bf16(avp, bvp, pacc[rt], 0, 0, 0);
        }
    }

    // epilogue: fp32 density term + bias, coalesced 128B stores
#pragma unroll
    for (int rt = 0; rt < 4; ++rt) {
        const int r = rt * 32 + l31;
        const float w0v = W[r * 65];
        const float bv  = bias[r];
#pragma unroll
        for (int reg = 0; reg < 16; ++reg) {
            const int row = (reg & 3) + 8 * (reg >> 2) + 4 * g;
            out[((size_t)(m0 + row) * BATCH + b) * RDIM + r]
                = pacc[rt][reg] + drow[reg] * w0v + bv;
        }
    }
}

extern "C" void kernel_launch(void* const* d_in, const int* in_sizes, int n_in,
                              void* d_out, int out_size, void* d_ws, size_t ws_size,
                              hipStream_t stream) {
    const float* ci   = (const float*)d_in[0];  // context_in  (N,B,1)
    const float* co   = (const float*)d_in[1];  // context_out (N,B,64)
    const float* ti   = (const float*)d_in[2];  // target_in   (M,B,1)
    const float* ls   = (const float*)d_in[3];  // lengthscale (1,)
    const float* W    = (const float*)d_in[4];  // (128,65)
    const float* bias = (const float*)d_in[5];  // (128,)
    float* o = (float*)d_out;                   // (M,B,128)
    (void)in_sizes; (void)n_in; (void)out_size; (void)ws_size;

    convdeepset_prep<<<4225, 256, 0, stream>>>(ci, co, ls, W, (unsigned char*)d_ws);
    convdeepset_main<<<BATCH * (M_TGT / 64), 128, 0, stream>>>(
        ti, ls, W, bias, (const unsigned char*)d_ws, o);
}

// Round 4
// 124.294 us; speedup vs baseline: 1.1559x; 1.1559x over previous
//
#include <hip/hip_runtime.h>
#include <hip/hip_bf16.h>

// ConvDeepSet, two-kernel scheme (round 4: 16x16x32 MFMA, 4 waves/SIMD, 2-deep prefetch):
//  prep:  co fp32 -> bf16 in frag chunk layout [b][n>>3][c][n&7] (ws, 4MB)
//         sx[b][n] = s * x[n][b] fp32,  s = sqrt(0.5*log2e)/ls
//         Wt[:,1:] -> bf16 frag layout [ch][r][8c]
//  main:  wave = 16 m, full N. K generated in-register in A-frag layout
//         (A[m=lane&15][k=(lane>>4)*8+j]); V = K @ co via 4x 16x16x32 bf16 MFMA
//         per 32-n step; dens exact fp32; projection 65->128 also 16x16x32 MFMA.

#define N_CTX 2048
#define BATCH 16
#define M_TGT 4096
#define COUT  64
#define RDIM  128

#define WS_CO_BYTES (N_CTX * BATCH * COUT * 2)        // 4 MB
#define WS_SX_OFF   WS_CO_BYTES                        // 128 KB fp32
#define WS_WT_OFF   (WS_SX_OFF + N_CTX * BATCH * 4)    // 16 KB bf16

#define SSCALE 0.8493222f   // sqrt(0.5 * log2(e))

typedef __attribute__((ext_vector_type(8)))  short        bf16x8;
typedef __attribute__((ext_vector_type(4)))  float        floatx4;
typedef __attribute__((ext_vector_type(4)))  unsigned int uint4v;

#if __has_builtin(__builtin_amdgcn_exp2f)
#define EXP2F __builtin_amdgcn_exp2f
#else
#define EXP2F exp2f
#endif

static __device__ __forceinline__ unsigned int pack_bf16(float lo, float hi) {
    __hip_bfloat162 h = __float22bfloat162_rn(make_float2(lo, hi));
    return *reinterpret_cast<unsigned int*>(&h);
}
static __device__ __forceinline__ unsigned short f2bf(float f) {
    __hip_bfloat16 h = __float2bfloat16(f);
    return *reinterpret_cast<unsigned short*>(&h);
}

__global__ __launch_bounds__(256)
void convdeepset_prep(const float* __restrict__ ci, const float* __restrict__ co,
                      const float* __restrict__ ls, const float* __restrict__ W,
                      unsigned char* __restrict__ ws)
{
    unsigned short* cow = (unsigned short*)ws;
    float*          sx  = (float*)(ws + WS_SX_OFF);
    unsigned short* wt  = (unsigned short*)(ws + WS_WT_OFF);
    const int blk = blockIdx.x, tid = threadIdx.x;

    if (blk < 1024) {
        // co: 1M n-pairs, 4 per thread; reads coalesced along c, 4B writes stride 16B
#pragma unroll
        for (int it = 0; it < 4; ++it) {
            const int f  = (it * 1024 + blk) * 256 + tid;
            const int c  = f & 63;
            const int bb = (f >> 6) & 15;
            const int n  = (f >> 10) * 2;
            const float f0 = co[((size_t)n       * BATCH + bb) * COUT + c];
            const float f1 = co[((size_t)(n + 1) * BATCH + bb) * COUT + c];
            *(unsigned int*)&cow[bb * 131072 + (n >> 3) * 512 + c * 8 + (n & 7)]
                = pack_bf16(f0, f1);
        }
    } else if (blk < 1152) {
        const int f = (blk - 1024) * 256 + tid;   // 0..32767
        const int n = f & 2047, bb = f >> 11;
        const float s = SSCALE / ls[0];
        sx[bb * 2048 + n] = s * ci[(size_t)n * BATCH + bb];
    } else {
        for (int f = tid; f < 8192; f += 256) {
            const int cp = f & 7, r = (f >> 3) & 127, ch = f >> 10;
            wt[ch * 1024 + r * 8 + cp] = f2bf(W[r * 65 + 1 + ch * 8 + cp]);
        }
    }
}

__global__ __launch_bounds__(256)
void convdeepset_main(const float* __restrict__ ti, const float* __restrict__ ls,
                      const float* __restrict__ W,  const float* __restrict__ bias,
                      const unsigned char* __restrict__ ws, float* __restrict__ out)
{
    __shared__ float sxt[N_CTX];                 // 8 KB  scaled x, whole batch
    __shared__ unsigned short vstage[4][1024];   // 8 KB  per-wave V (16m x 64c), A-frag
    __shared__ float w0l[RDIM], biasl[RDIM];     // 1 KB

    const int tid  = threadIdx.x;
    const int lane = tid & 63;
    const int wv   = tid >> 6;        // 0..3
    const int g2   = lane >> 4;       // k-group 0..3
    const int l15  = lane & 15;
    const int b    = blockIdx.x >> 6; // 0..15
    const int mt   = blockIdx.x & 63; // 0..63
    const int m0   = mt * 64 + wv * 16;

    // stage scaled x (coalesced float4, 512 float4s) + w0/bias tables
    const float4* sxg = (const float4*)(ws + WS_SX_OFF) + b * (N_CTX / 4);
    float4* s4 = (float4*)sxt;
    s4[tid]       = sxg[tid];
    s4[tid + 256] = sxg[tid + 256];
    if (tid < RDIM) { w0l[tid] = W[tid * 65]; biasl[tid] = bias[tid]; }

    const float s  = SSCALE / ls[0];
    const float sy = s * ti[(size_t)(m0 + l15) * BATCH + b];
    __syncthreads();

    // B-frag stream base: lane reads chunk (ks*4+g2), c = q*16+l15, 8 bf16 contiguous
    const unsigned short* cowB = (const unsigned short*)ws
                               + (size_t)b * 131072 + g2 * 512 + l15 * 8;

    floatx4 acc[4];
#pragma unroll
    for (int q = 0; q < 4; ++q)
#pragma unroll
        for (int i = 0; i < 4; ++i) acc[q][i] = 0.0f;
    float dp0 = 0.0f, dp1 = 0.0f;

    // depth-2 prefetch buffers
    bf16x8 A0, A1, A2, A3, B0, B1, B2, B3;
    float4 Axa, Axb, Bxa, Bxb;
    {
        const unsigned short* p = cowB;
        A0 = *(const bf16x8*)(p);       A1 = *(const bf16x8*)(p + 128);
        A2 = *(const bf16x8*)(p + 256); A3 = *(const bf16x8*)(p + 384);
        Axa = *(const float4*)&sxt[g2 * 8]; Axb = *(const float4*)&sxt[g2 * 8 + 4];
        p = cowB + 2048;
        B0 = *(const bf16x8*)(p);       B1 = *(const bf16x8*)(p + 128);
        B2 = *(const bf16x8*)(p + 256); B3 = *(const bf16x8*)(p + 384);
        Bxa = *(const float4*)&sxt[32 + g2 * 8]; Bxb = *(const float4*)&sxt[32 + g2 * 8 + 4];
    }

    auto kstep = [&](bf16x8& b0, bf16x8& b1, bf16x8& b2, bf16x8& b3,
                     float4& xa, float4& xb, int kpre) {
        const bf16x8 c0 = b0, c1 = b1, c2 = b2, c3 = b3;
        const float4 ca = xa, cb = xb;
        // issue prefetch for k-step kpre before compute
        const unsigned short* p = cowB + kpre * 2048;
        b0 = *(const bf16x8*)(p);       b1 = *(const bf16x8*)(p + 128);
        b2 = *(const bf16x8*)(p + 256); b3 = *(const bf16x8*)(p + 384);
        const float* xp = &sxt[kpre * 32 + g2 * 8];
        xa = *(const float4*)(xp); xb = *(const float4*)(xp + 4);
        // compute: 8 exps -> A-frag
        const float x0 = ca.x, x1 = ca.y, x2 = ca.z, x3 = ca.w;
        const float x4 = cb.x, x5 = cb.y, x6 = cb.z, x7 = cb.w;
        float kv[8];
        {
            float t;
            t = x0 - sy; kv[0] = EXP2F(-(t * t));
            t = x1 - sy; kv[1] = EXP2F(-(t * t));
            t = x2 - sy; kv[2] = EXP2F(-(t * t));
            t = x3 - sy; kv[3] = EXP2F(-(t * t));
            t = x4 - sy; kv[4] = EXP2F(-(t * t));
            t = x5 - sy; kv[5] = EXP2F(-(t * t));
            t = x6 - sy; kv[6] = EXP2F(-(t * t));
            t = x7 - sy; kv[7] = EXP2F(-(t * t));
        }
        dp0 += (kv[0] + kv[1]) + (kv[2] + kv[3]);   // density exact fp32
        dp1 += (kv[4] + kv[5]) + (kv[6] + kv[7]);
        uint4v aw;
#pragma unroll
        for (int q2 = 0; q2 < 4; ++q2) aw[q2] = pack_bf16(kv[2 * q2], kv[2 * q2 + 1]);
        const bf16x8 av = __builtin_bit_cast(bf16x8, aw);
        acc[0] = __builtin_amdgcn_mfma_f32_16x16x32_bf16(av, c0, acc[0], 0, 0, 0);
        acc[1] = __builtin_amdgcn_mfma_f32_16x16x32_bf16(av, c1, acc[1], 0, 0, 0);
        acc[2] = __builtin_amdgcn_mfma_f32_16x16x32_bf16(av, c2, acc[2], 0, 0, 0);
        acc[3] = __builtin_amdgcn_mfma_f32_16x16x32_bf16(av, c3, acc[3], 0, 0, 0);
    };

    for (int ks = 0; ks < 64; ks += 2) {
        kstep(A0, A1, A2, A3, Axa, Axb, (ks + 2 < 64) ? ks + 2 : 63);
        kstep(B0, B1, B2, B3, Bxa, Bxb, (ks + 3 < 64) ? ks + 3 : 63);
    }

    // density: combine the 4 k-groups (lane^16 flips g2 bit0, lane^32 flips bit1)
    float dens = dp0 + dp1;
    dens += __shfl_xor(dens, 16);
    dens += __shfl_xor(dens, 32);    // now every lane holds dens[m = m0 + l15]

    // normalize channels, stage V (bf16, A-frag layout) to this wave's LDS region
    float drow[4];
    unsigned short* vs = vstage[wv];
#pragma unroll
    for (int reg = 0; reg < 4; ++reg) {
        const int m = (lane >> 4) * 4 + reg;      // C/D map: col=lane&15, row=(lane>>4)*4+reg
        const float dr = __shfl(dens, m);
        drow[reg] = dr;
        const float dinv = 1.0f / (dr + 1e-8f);
#pragma unroll
        for (int q = 0; q < 4; ++q) {
            const int c = q * 16 + l15;
            vs[(c >> 3) * 128 + m * 8 + (c & 7)] = f2bf(acc[q][reg] * dinv);
        }
    }

    // projection: D[16m][128r] = V[16m][64c] @ Wt[64c][128r], same-wave LDS (no barrier)
    const unsigned short* wtg = (const unsigned short*)(ws + WS_WT_OFF);
    floatx4 pacc[8];
#pragma unroll
    for (int rt = 0; rt < 8; ++rt)
#pragma unroll
        for (int i = 0; i < 4; ++i) pacc[rt][i] = 0.0f;

#pragma unroll
    for (int s2 = 0; s2 < 2; ++s2) {
        const int ch = s2 * 4 + g2;
        const bf16x8 avp = *(const bf16x8*)&vs[ch * 128 + l15 * 8];
#pragma unroll
        for (int rt = 0; rt < 8; ++rt) {
            const bf16x8 bvp = *(const bf16x8*)&wtg[ch * 1024 + (rt * 16 + l15) * 8];
            pacc[rt] = __builtin_amdgcn_mfma_f32_16x16x32_bf16(avp, bvp, pacc[rt], 0, 0, 0);
        }
    }

    // epilogue: fp32 density term + bias
#pragma unroll
    for (int rt = 0; rt < 8; ++rt) {
        const int r = rt * 16 + l15;
        const float w0v = w0l[r];
        const float bv  = biasl[r];
#pragma unroll
        for (int reg = 0; reg < 4; ++reg) {
            const int m = (lane >> 4) * 4 + reg;
            out[((size_t)(m0 + m) * BATCH + b) * RDIM + r]
                = pacc[rt][reg] + drow[reg] * w0v + bv;
        }
    }
}

extern "C" void kernel_launch(void* const* d_in, const int* in_sizes, int n_in,
                              void* d_out, int out_size, void* d_ws, size_t ws_size,
                              hipStream_t stream) {
    const float* ci   = (const float*)d_in[0];  // context_in  (N,B,1)
    const float* co   = (const float*)d_in[1];  // context_out (N,B,64)
    const float* ti   = (const float*)d_in[2];  // target_in   (M,B,1)
    const float* ls   = (const float*)d_in[3];  // lengthscale (1,)
    const float* W    = (const float*)d_in[4];  // (128,65)
    const float* bias = (const float*)d_in[5];  // (128,)
    float* o = (float*)d_out;                   // (M,B,128)
    (void)in_sizes; (void)n_in; (void)out_size; (void)ws_size;

    convdeepset_prep<<<1153, 256, 0, stream>>>(ci, co, ls, W, (unsigned char*)d_ws);
    convdeepset_main<<<BATCH * (M_TGT / 64), 256, 0, stream>>>(
        ti, ls, W, bias, (const unsigned char*)d_ws, o);
}

// Round 5
// 123.621 us; speedup vs baseline: 1.1622x; 1.0055x over previous
//
#include <hip/hip_runtime.h>
#include <hip/hip_bf16.h>

// ConvDeepSet round 5: N-split x2 (8192 waves), dens via MFMA (ones B-frag),
// XCD-aware batch swizzle, post-projection normalization.
//  prep:  co fp32 -> bf16 frag chunk layout [b][n>>3][c][n&7] (ws, 4MB, coalesced both sides)
//         sx[b][n] = s*x[n][b] fp32;  Wt[:,1:] bf16 frag layout [ch][r][8c]
//  main:  block = 4 waves: wv&1 = m-tile (16 m), wv>>1 = n-half (1024 n).
//         K generated in-register in A-frag layout; V,dens via 16x16x32 bf16 MFMA;
//         partner waves combine partial V (bf16) + dens (fp32) through LDS;
//         projection 65->128 MFMA on unnormalized V; divide by dens in epilogue.

#define N_CTX 2048
#define BATCH 16
#define M_TGT 4096
#define COUT  64
#define RDIM  128

#define WS_CO_BYTES (N_CTX * BATCH * COUT * 2)        // 4 MB
#define WS_SX_OFF   WS_CO_BYTES                        // 128 KB fp32
#define WS_WT_OFF   (WS_SX_OFF + N_CTX * BATCH * 4)    // 16 KB bf16

#define SSCALE 0.8493222f   // sqrt(0.5 * log2(e))

typedef __attribute__((ext_vector_type(8)))  short        bf16x8;
typedef __attribute__((ext_vector_type(4)))  float        floatx4;
typedef __attribute__((ext_vector_type(4)))  unsigned int uint4v;

#if __has_builtin(__builtin_amdgcn_exp2f)
#define EXP2F __builtin_amdgcn_exp2f
#else
#define EXP2F exp2f
#endif

static __device__ __forceinline__ unsigned int pack_bf16(float lo, float hi) {
    __hip_bfloat162 h = __float22bfloat162_rn(make_float2(lo, hi));
    return *reinterpret_cast<unsigned int*>(&h);
}
static __device__ __forceinline__ unsigned short f2bf(float f) {
    __hip_bfloat16 h = __float2bfloat16(f);
    return *reinterpret_cast<unsigned short*>(&h);
}

__global__ __launch_bounds__(256)
void convdeepset_prep(const float* __restrict__ ci, const float* __restrict__ co,
                      const float* __restrict__ ls, const float* __restrict__ W,
                      unsigned char* __restrict__ ws)
{
    unsigned short* cow = (unsigned short*)ws;
    float*          sx  = (float*)(ws + WS_SX_OFF);
    unsigned short* wt  = (unsigned short*)(ws + WS_WT_OFF);
    const int blk = blockIdx.x, tid = threadIdx.x;

    if (blk < 1024) {
        // group = (bb, nblk of 8 n); lane = c. Reads coalesced (256B/row),
        // writes fully coalesced dwordx4 (lane-contiguous 16B each).
        const int g    = blk * 4 + (tid >> 6);
        const int bb   = g & 15;
        const int nblk = g >> 4;           // 0..255
        const int c    = tid & 63;
        const float* rp = co + ((size_t)nblk * 8 * BATCH + bb) * COUT + c;
        unsigned int u[4];
#pragma unroll
        for (int j = 0; j < 4; ++j) {
            const float f0 = rp[(size_t)(2 * j)     * BATCH * COUT];
            const float f1 = rp[(size_t)(2 * j + 1) * BATCH * COUT];
            u[j] = pack_bf16(f0, f1);
        }
        *(uint4v*)&cow[(size_t)bb * 131072 + nblk * 512 + c * 8] = *(uint4v*)u;
    } else if (blk < 1152) {
        const int f = (blk - 1024) * 256 + tid;   // 0..32767
        const int n = f & 2047, bb = f >> 11;
        const float s = SSCALE / ls[0];
        sx[bb * 2048 + n] = s * ci[(size_t)n * BATCH + bb];
    } else {
        for (int f = tid; f < 8192; f += 256) {
            const int cp = f & 7, r = (f >> 3) & 127, ch = f >> 10;
            wt[ch * 1024 + r * 8 + cp] = f2bf(W[r * 65 + 1 + ch * 8 + cp]);
        }
    }
}

__global__ __launch_bounds__(256, 7)
void convdeepset_main(const float* __restrict__ ti, const float* __restrict__ ls,
                      const float* __restrict__ W,  const float* __restrict__ bias,
                      const unsigned char* __restrict__ ws, float* __restrict__ out)
{
    __shared__ float sxt[N_CTX];                 //  8 KB  scaled x, whole batch
    __shared__ unsigned int rbuf[2 * 64 * 12];   //  6 KB  partner partials (8 bf16x2 + 4 f32)
    __shared__ unsigned short vstage[2][1024];   //  4 KB  V staging (waves 0,1), A-frag
    __shared__ float w0l[RDIM], biasl[RDIM];     //  1 KB
    // total 19.5 KB -> 8 blocks/CU

    const int tid  = threadIdx.x;
    const int lane = tid & 63;
    const int wv   = tid >> 6;        // 0..3
    const int mh   = wv & 1;          // m-tile within block
    const int nh   = wv >> 1;         // n-half
    const int g2   = lane >> 4;       // MFMA k-group 0..3
    const int l15  = lane & 15;

    // XCD swizzle: blk%8 ~ XCD (round-robin dispatch); 2 batches per XCD.
    const int xcd = blockIdx.x & 7;
    const int i   = blockIdx.x >> 3;  // 0..255
    const int b   = xcd * 2 + (i & 1);
    const int mt  = i >> 1;           // 0..127
    const int m0  = mt * 32 + mh * 16;

    // stage scaled x (coalesced float4) + epilogue tables
    const float4* sxg = (const float4*)(ws + WS_SX_OFF) + b * (N_CTX / 4);
    float4* s4 = (float4*)sxt;
    s4[tid]       = sxg[tid];
    s4[tid + 256] = sxg[tid + 256];
    if (tid < RDIM) { w0l[tid] = W[tid * 65]; biasl[tid] = bias[tid]; }

    const float s  = SSCALE / ls[0];
    const float sy = s * ti[(size_t)(m0 + l15) * BATCH + b];
    __syncthreads();

    // constant all-ones B-frag for the density MFMA
    const short onebf = (short)0x3F80;
    bf16x8 ones;
#pragma unroll
    for (int j = 0; j < 8; ++j) ones[j] = onebf;

    const int ks0 = nh * 32;
    const unsigned short* cowB = (const unsigned short*)ws
                               + (size_t)b * 131072 + (ks0 * 4 + g2) * 512 + l15 * 8;

    floatx4 acc[4], accd;
#pragma unroll
    for (int q = 0; q < 4; ++q)
#pragma unroll
        for (int e = 0; e < 4; ++e) acc[q][e] = 0.0f;
#pragma unroll
    for (int e = 0; e < 4; ++e) accd[e] = 0.0f;

#pragma unroll 2
    for (int ks = 0; ks < 32; ++ks) {
        const unsigned short* p = cowB + (size_t)ks * 2048;
        const bf16x8 c0 = *(const bf16x8*)(p);
        const bf16x8 c1 = *(const bf16x8*)(p + 128);
        const bf16x8 c2 = *(const bf16x8*)(p + 256);
        const bf16x8 c3 = *(const bf16x8*)(p + 384);
        const float* xp = &sxt[(ks0 + ks) * 32 + g2 * 8];
        const float4 xa = *(const float4*)(xp);
        const float4 xb = *(const float4*)(xp + 4);
        float kv[8];
        {
            float t;
            t = xa.x - sy; kv[0] = EXP2F(-(t * t));
            t = xa.y - sy; kv[1] = EXP2F(-(t * t));
            t = xa.z - sy; kv[2] = EXP2F(-(t * t));
            t = xa.w - sy; kv[3] = EXP2F(-(t * t));
            t = xb.x - sy; kv[4] = EXP2F(-(t * t));
            t = xb.y - sy; kv[5] = EXP2F(-(t * t));
            t = xb.z - sy; kv[6] = EXP2F(-(t * t));
            t = xb.w - sy; kv[7] = EXP2F(-(t * t));
        }
        uint4v aw;
#pragma unroll
        for (int q2 = 0; q2 < 4; ++q2) aw[q2] = pack_bf16(kv[2 * q2], kv[2 * q2 + 1]);
        const bf16x8 av = __builtin_bit_cast(bf16x8, aw);
        acc[0] = __builtin_amdgcn_mfma_f32_16x16x32_bf16(av, c0, acc[0], 0, 0, 0);
        acc[1] = __builtin_amdgcn_mfma_f32_16x16x32_bf16(av, c1, acc[1], 0, 0, 0);
        acc[2] = __builtin_amdgcn_mfma_f32_16x16x32_bf16(av, c2, acc[2], 0, 0, 0);
        acc[3] = __builtin_amdgcn_mfma_f32_16x16x32_bf16(av, c3, acc[3], 0, 0, 0);
        accd   = __builtin_amdgcn_mfma_f32_16x16x32_bf16(av, ones, accd, 0, 0, 0);
    }

    // ---- cross-wave combine: n-half 1 publishes partials, n-half 0 reduces ----
    if (nh == 1) {
        unsigned int* slot = &rbuf[(mh * 64 + lane) * 12];
        unsigned int pu[8];
#pragma unroll
        for (int reg = 0; reg < 4; ++reg)
#pragma unroll
            for (int qp = 0; qp < 2; ++qp)
                pu[reg * 2 + qp] = pack_bf16(acc[2 * qp][reg], acc[2 * qp + 1][reg]);
        *(uint4v*)(slot)     = *(uint4v*)(pu);
        *(uint4v*)(slot + 4) = *(uint4v*)(pu + 4);
        *(uint4v*)(slot + 8) = __builtin_bit_cast(uint4v, accd);
    }
    __syncthreads();
    if (nh == 1) return;

    {
        const unsigned int* slot = &rbuf[(mh * 64 + lane) * 12];
        const uint4v r0 = *(const uint4v*)(slot);
        const uint4v r1 = *(const uint4v*)(slot + 4);
        const floatx4 rd = __builtin_bit_cast(floatx4, *(const uint4v*)(slot + 8));
#pragma unroll
        for (int reg = 0; reg < 4; ++reg)
#pragma unroll
            for (int qp = 0; qp < 2; ++qp) {
                const int j = reg * 2 + qp;
                const unsigned int u = (j < 4) ? r0[j] : r1[j - 4];
                acc[2 * qp][reg]     += __builtin_bit_cast(float, u << 16);
                acc[2 * qp + 1][reg] += __builtin_bit_cast(float, u & 0xffff0000u);
            }
#pragma unroll
        for (int e = 0; e < 4; ++e) accd[e] += rd[e];
    }

    float drow[4], dinv[4];
#pragma unroll
    for (int reg = 0; reg < 4; ++reg) {
        drow[reg] = accd[reg];
        dinv[reg] = 1.0f / (accd[reg] + 1e-8f);
    }

    // stage unnormalized V (bf16, A-frag layout); /(dens+eps) commutes with projection
    unsigned short* vs = vstage[mh];
#pragma unroll
    for (int reg = 0; reg < 4; ++reg) {
        const int m = (lane >> 4) * 4 + reg;      // C/D map: col=lane&15, row=(lane>>4)*4+reg
#pragma unroll
        for (int q = 0; q < 4; ++q) {
            const int c = q * 16 + l15;
            vs[(c >> 3) * 128 + m * 8 + (c & 7)] = f2bf(acc[q][reg]);
        }
    }

    // projection: D[16m][128r] = V[16m][64c] @ Wt[64c][128r], same-wave LDS (no barrier)
    const unsigned short* wtg = (const unsigned short*)(ws + WS_WT_OFF);
    floatx4 pacc[8];
#pragma unroll
    for (int rt = 0; rt < 8; ++rt)
#pragma unroll
        for (int e = 0; e < 4; ++e) pacc[rt][e] = 0.0f;

#pragma unroll
    for (int s2 = 0; s2 < 2; ++s2) {
        const int ch = s2 * 4 + g2;
        const bf16x8 avp = *(const bf16x8*)&vs[ch * 128 + l15 * 8];
#pragma unroll
        for (int rt = 0; rt < 8; ++rt) {
            const bf16x8 bvp = *(const bf16x8*)&wtg[ch * 1024 + (rt * 16 + l15) * 8];
            pacc[rt] = __builtin_amdgcn_mfma_f32_16x16x32_bf16(avp, bvp, pacc[rt], 0, 0, 0);
        }
    }

    // epilogue: out = pacc/dens + dens*W0 + bias
#pragma unroll
    for (int rt = 0; rt < 8; ++rt) {
        const int r = rt * 16 + l15;
        const float w0v = w0l[r];
        const float bv  = biasl[r];
#pragma unroll
        for (int reg = 0; reg < 4; ++reg) {
            const int m = (lane >> 4) * 4 + reg;
            out[((size_t)(m0 + m) * BATCH + b) * RDIM + r]
                = pacc[rt][reg] * dinv[reg] + drow[reg] * w0v + bv;
        }
    }
}

extern "C" void kernel_launch(void* const* d_in, const int* in_sizes, int n_in,
                              void* d_out, int out_size, void* d_ws, size_t ws_size,
                              hipStream_t stream) {
    const float* ci   = (const float*)d_in[0];  // context_in  (N,B,1)
    const float* co   = (const float*)d_in[1];  // context_out (N,B,64)
    const float* ti   = (const float*)d_in[2];  // target_in   (M,B,1)
    const float* ls   = (const float*)d_in[3];  // lengthscale (1,)
    const float* W    = (const float*)d_in[4];  // (128,65)
    const float* bias = (const float*)d_in[5];  // (128,)
    float* o = (float*)d_out;                   // (M,B,128)
    (void)in_sizes; (void)n_in; (void)out_size; (void)ws_size;

    convdeepset_prep<<<1153, 256, 0, stream>>>(ci, co, ls, W, (unsigned char*)d_ws);
    convdeepset_main<<<2048, 256, 0, stream>>>(
        ti, ls, W, bias, (const unsigned char*)d_ws, o);
}

// Round 6
// 121.964 us; speedup vs baseline: 1.1780x; 1.0136x over previous
//
#include <hip/hip_runtime.h>
#include <hip/hip_bf16.h>

// ConvDeepSet round 6: B-stream BW attack.
//  - prep: co fp32 -> bf16 frag chunk layout [b][n>>3][c][n&7] (ws, 4MB);
//          sx[b][n] = s*x[n][b]; Wt[:,1:] bf16 frag layout [ch][r][8c].
//  - main: block = 4 waves x 32 m = 128 m, full N. co stream staged into LDS
//          via async global_load_lds (16B), double-buffered 16KB slabs
//          (4 ksteps/period, 16 barriers), shared by all 4 waves.
//          Each wave: 2 A-frags (sy0/sy1) per B-frag -> 8 V-MFMA + 2 dens-MFMA
//          per kstep. Post-projection normalization; dens via MFMA-with-ones.

#define N_CTX 2048
#define BATCH 16
#define M_TGT 4096
#define COUT  64
#define RDIM  128

#define WS_CO_BYTES (N_CTX * BATCH * COUT * 2)        // 4 MB
#define WS_SX_OFF   WS_CO_BYTES                        // 128 KB fp32
#define WS_WT_OFF   (WS_SX_OFF + N_CTX * BATCH * 4)    // 16 KB bf16

#define SSCALE 0.8493222f   // sqrt(0.5 * log2(e))

typedef __attribute__((ext_vector_type(8)))  short        bf16x8;
typedef __attribute__((ext_vector_type(4)))  float        floatx4;
typedef __attribute__((ext_vector_type(4)))  unsigned int uint4v;

#if __has_builtin(__builtin_amdgcn_exp2f)
#define EXP2F __builtin_amdgcn_exp2f
#else
#define EXP2F exp2f
#endif

static __device__ __forceinline__ unsigned int pack_bf16(float lo, float hi) {
    __hip_bfloat162 h = __float22bfloat162_rn(make_float2(lo, hi));
    return *reinterpret_cast<unsigned int*>(&h);
}
static __device__ __forceinline__ unsigned short f2bf(float f) {
    __hip_bfloat16 h = __float2bfloat16(f);
    return *reinterpret_cast<unsigned short*>(&h);
}

__global__ __launch_bounds__(256)
void convdeepset_prep(const float* __restrict__ ci, const float* __restrict__ co,
                      const float* __restrict__ ls, const float* __restrict__ W,
                      unsigned char* __restrict__ ws)
{
    unsigned short* cow = (unsigned short*)ws;
    float*          sx  = (float*)(ws + WS_SX_OFF);
    unsigned short* wt  = (unsigned short*)(ws + WS_WT_OFF);
    const int blk = blockIdx.x, tid = threadIdx.x;

    if (blk < 1024) {
        // group = (bb, nblk of 8 n); lane = c. Reads coalesced (256B/row),
        // writes fully coalesced dwordx4.
        const int g    = blk * 4 + (tid >> 6);
        const int bb   = g & 15;
        const int nblk = g >> 4;           // 0..255
        const int c    = tid & 63;
        const float* rp = co + ((size_t)nblk * 8 * BATCH + bb) * COUT + c;
        unsigned int u[4];
#pragma unroll
        for (int j = 0; j < 4; ++j) {
            const float f0 = rp[(size_t)(2 * j)     * BATCH * COUT];
            const float f1 = rp[(size_t)(2 * j + 1) * BATCH * COUT];
            u[j] = pack_bf16(f0, f1);
        }
        *(uint4v*)&cow[(size_t)bb * 131072 + nblk * 512 + c * 8] = *(uint4v*)u;
    } else if (blk < 1152) {
        const int f = (blk - 1024) * 256 + tid;   // 0..32767
        const int n = f & 2047, bb = f >> 11;
        const float s = SSCALE / ls[0];
        sx[bb * 2048 + n] = s * ci[(size_t)n * BATCH + bb];
    } else {
        for (int f = tid; f < 8192; f += 256) {
            const int cp = f & 7, r = (f >> 3) & 127, ch = f >> 10;
            wt[ch * 1024 + r * 8 + cp] = f2bf(W[r * 65 + 1 + ch * 8 + cp]);
        }
    }
}

__global__ __launch_bounds__(256)
void convdeepset_main(const float* __restrict__ ti, const float* __restrict__ ls,
                      const float* __restrict__ W,  const float* __restrict__ bias,
                      const unsigned char* __restrict__ ws, float* __restrict__ out)
{
    __shared__ float sxt[N_CTX];                  //  8 KB scaled x, whole batch
    __shared__ unsigned short slab[2][8192];      // 32 KB double-buffered B stream
    __shared__ unsigned short vstage[4][2][1024]; // 16 KB V staging, A-frag layout
    __shared__ float w0l[RDIM], biasl[RDIM];      //  1 KB
    // 57 KB -> 2 blocks/CU (grid is 2/CU anyway)

    const int tid  = threadIdx.x;
    const int lane = tid & 63;
    const int wv   = tid >> 6;        // 0..3
    const int g2   = lane >> 4;       // MFMA k-group 0..3
    const int l15  = lane & 15;

    // XCD swizzle: 2 batches pinned per XCD (round-robin dispatch by blk&7)
    const int xcd = blockIdx.x & 7;
    const int i   = blockIdx.x >> 3;  // 0..63
    const int b   = xcd * 2 + (i & 1);
    const int mt  = i >> 1;           // 0..31
    const int m0  = mt * 128 + wv * 32;

    // stage scaled x (coalesced float4) + epilogue tables
    const float4* sxg = (const float4*)(ws + WS_SX_OFF) + b * (N_CTX / 4);
    ((float4*)sxt)[tid]       = sxg[tid];
    ((float4*)sxt)[tid + 256] = sxg[tid + 256];
    if (tid < RDIM) { w0l[tid] = W[tid * 65]; biasl[tid] = bias[tid]; }

    const float s   = SSCALE / ls[0];
    const float sy0 = s * ti[(size_t)(m0 + l15) * BATCH + b];
    const float sy1 = s * ti[(size_t)(m0 + 16 + l15) * BATCH + b];

    const unsigned short* cowb = (const unsigned short*)ws + (size_t)b * 131072;

    // async staging: period p = 16 contiguous 1KB chunks; each wave DMAs 4
    typedef const __attribute__((address_space(1))) unsigned int* gp_t;
    typedef __attribute__((address_space(3))) unsigned int* lp_t;
    auto stage = [&](int period, int buf) {
        const unsigned short* gsrc = cowb + (size_t)period * 8192;
#pragma unroll
        for (int j = 0; j < 4; ++j) {
            const int ch = wv * 4 + j;
            __builtin_amdgcn_global_load_lds((gp_t)(gsrc + ch * 512 + lane * 8),
                                             (lp_t)(&slab[buf][ch * 512]),
                                             16, 0, 0);
        }
    };

    const short onebf = (short)0x3F80;
    bf16x8 ones;
#pragma unroll
    for (int j = 0; j < 8; ++j) ones[j] = onebf;

    floatx4 acc0[4], acc1[4], accd0, accd1;
#pragma unroll
    for (int q = 0; q < 4; ++q)
#pragma unroll
        for (int e = 0; e < 4; ++e) { acc0[q][e] = 0.0f; acc1[q][e] = 0.0f; }
#pragma unroll
    for (int e = 0; e < 4; ++e) { accd0[e] = 0.0f; accd1[e] = 0.0f; }

    stage(0, 0);
    __syncthreads();   // drains DMA (vmcnt) + sxt visible

    for (int p = 0; p < 16; ++p) {
        if (p + 1 < 16) stage(p + 1, (p + 1) & 1);    // async into other slab
        const unsigned short* sb = &slab[p & 1][0];
#pragma unroll
        for (int k2 = 0; k2 < 4; ++k2) {
            const int ks = p * 4 + k2;
            const float* xp = &sxt[ks * 32 + g2 * 8];
            const float4 xa = *(const float4*)(xp);
            const float4 xb = *(const float4*)(xp + 4);
            const unsigned short* bp = sb + (k2 * 4 + g2) * 512 + l15 * 8;
            const bf16x8 c0 = *(const bf16x8*)(bp);
            const bf16x8 c1 = *(const bf16x8*)(bp + 128);
            const bf16x8 c2 = *(const bf16x8*)(bp + 256);
            const bf16x8 c3 = *(const bf16x8*)(bp + 384);
            const float xs[8] = {xa.x, xa.y, xa.z, xa.w, xb.x, xb.y, xb.z, xb.w};
            float kv0[8], kv1[8];
#pragma unroll
            for (int j = 0; j < 8; ++j) {
                float t0 = xs[j] - sy0; kv0[j] = EXP2F(-(t0 * t0));
                float t1 = xs[j] - sy1; kv1[j] = EXP2F(-(t1 * t1));
            }
            uint4v aw0, aw1;
#pragma unroll
            for (int q = 0; q < 4; ++q) {
                aw0[q] = pack_bf16(kv0[2 * q], kv0[2 * q + 1]);
                aw1[q] = pack_bf16(kv1[2 * q], kv1[2 * q + 1]);
            }
            const bf16x8 av0 = __builtin_bit_cast(bf16x8, aw0);
            const bf16x8 av1 = __builtin_bit_cast(bf16x8, aw1);
            acc0[0] = __builtin_amdgcn_mfma_f32_16x16x32_bf16(av0, c0, acc0[0], 0, 0, 0);
            acc0[1] = __builtin_amdgcn_mfma_f32_16x16x32_bf16(av0, c1, acc0[1], 0, 0, 0);
            acc0[2] = __builtin_amdgcn_mfma_f32_16x16x32_bf16(av0, c2, acc0[2], 0, 0, 0);
            acc0[3] = __builtin_amdgcn_mfma_f32_16x16x32_bf16(av0, c3, acc0[3], 0, 0, 0);
            accd0   = __builtin_amdgcn_mfma_f32_16x16x32_bf16(av0, ones, accd0, 0, 0, 0);
            acc1[0] = __builtin_amdgcn_mfma_f32_16x16x32_bf16(av1, c0, acc1[0], 0, 0, 0);
            acc1[1] = __builtin_amdgcn_mfma_f32_16x16x32_bf16(av1, c1, acc1[1], 0, 0, 0);
            acc1[2] = __builtin_amdgcn_mfma_f32_16x16x32_bf16(av1, c2, acc1[2], 0, 0, 0);
            acc1[3] = __builtin_amdgcn_mfma_f32_16x16x32_bf16(av1, c3, acc1[3], 0, 0, 0);
            accd1   = __builtin_amdgcn_mfma_f32_16x16x32_bf16(av1, ones, accd1, 0, 0, 0);
        }
        __syncthreads();   // slab handoff (drains next-slab DMA too)
    }

    // ---- per m-tile: stage V, project, store ----
    const unsigned short* wtg = (const unsigned short*)(ws + WS_WT_OFF);
#pragma unroll
    for (int tile = 0; tile < 2; ++tile) {
        const floatx4* acc  = tile ? acc1 : acc0;
        const floatx4  accd = tile ? accd1 : accd0;
        float drow[4], dinv[4];
#pragma unroll
        for (int e = 0; e < 4; ++e) {
            drow[e] = accd[e];                       // dens[m=row], all cols equal
            dinv[e] = 1.0f / (accd[e] + 1e-8f);
        }
        unsigned short* vs = vstage[wv][tile];
#pragma unroll
        for (int reg = 0; reg < 4; ++reg) {
            const int m = (lane >> 4) * 4 + reg;     // C/D map: col=lane&15, row=(lane>>4)*4+reg
#pragma unroll
            for (int q = 0; q < 4; ++q) {
                const int c = q * 16 + l15;
                vs[(c >> 3) * 128 + m * 8 + (c & 7)] = f2bf(acc[q][reg]);
            }
        }
        // projection: D[16m][128r] = V @ Wt, same-wave LDS (no barrier)
        floatx4 pacc[8];
#pragma unroll
        for (int rt = 0; rt < 8; ++rt)
#pragma unroll
            for (int e = 0; e < 4; ++e) pacc[rt][e] = 0.0f;
#pragma unroll
        for (int s2 = 0; s2 < 2; ++s2) {
            const int ch = s2 * 4 + g2;
            const bf16x8 avp = *(const bf16x8*)&vs[ch * 128 + l15 * 8];
#pragma unroll
            for (int rt = 0; rt < 8; ++rt) {
                const bf16x8 bvp = *(const bf16x8*)&wtg[ch * 1024 + (rt * 16 + l15) * 8];
                pacc[rt] = __builtin_amdgcn_mfma_f32_16x16x32_bf16(avp, bvp, pacc[rt], 0, 0, 0);
            }
        }
        // epilogue: out = pacc/dens + dens*W0 + bias
#pragma unroll
        for (int rt = 0; rt < 8; ++rt) {
            const int r = rt * 16 + l15;
            const float w0v = w0l[r];
            const float bv  = biasl[r];
#pragma unroll
            for (int reg = 0; reg < 4; ++reg) {
                const int m = (lane >> 4) * 4 + reg;
                out[((size_t)(m0 + tile * 16 + m) * BATCH + b) * RDIM + r]
                    = pacc[rt][reg] * dinv[reg] + drow[reg] * w0v + bv;
            }
        }
    }
}

extern "C" void kernel_launch(void* const* d_in, const int* in_sizes, int n_in,
                              void* d_out, int out_size, void* d_ws, size_t ws_size,
                              hipStream_t stream) {
    const float* ci   = (const float*)d_in[0];  // context_in  (N,B,1)
    const float* co   = (const float*)d_in[1];  // context_out (N,B,64)
    const float* ti   = (const float*)d_in[2];  // target_in   (M,B,1)
    const float* ls   = (const float*)d_in[3];  // lengthscale (1,)
    const float* W    = (const float*)d_in[4];  // (128,65)
    const float* bias = (const float*)d_in[5];  // (128,)
    float* o = (float*)d_out;                   // (M,B,128)
    (void)in_sizes; (void)n_in; (void)out_size; (void)ws_size;

    convdeepset_prep<<<1153, 256, 0, stream>>>(ci, co, ls, W, (unsigned char*)d_ws);
    convdeepset_main<<<512, 256, 0, stream>>>(
        ti, ls, W, bias, (const unsigned char*)d_ws, o);
}